// Round 1
// baseline (580.265 us; speedup 1.0000x reference)
//
#include <hip/hip_runtime.h>
#include <cstdint>
#include <cstddef>

// ---------------------------------------------------------------------------
// SOMFNN forward: h = sigmoid(sigmoid(x@W0.T+b0)@W1.T+b1), plus per-layer
// ALMMo codebook lamb. Key simplifications (provably exact vs reference):
//   * SENc==cn2 always  =>  stau = base/2, constant scalar per layer.
//   * prototypes are never updated => all distances come from the Gram matrix
//     G = X X^T:  dist(i,j) = SEN[i]+SEN[j]-2 G[i,j].
//   * sample i is NEW iff no earlier PROTOTYPE j has dens>=DELTA. Parallel
//     pre-pass: e_i = any j<i with dens>=DELTA  (e_i=0 => definitively NEW).
//     The e_i=1 stragglers (expected: none for this data) are resolved
//     exactly by a single-block sequential pass.
// ---------------------------------------------------------------------------

#define DELTA_F 0.13533528323661270f  // float(exp(-2))
#define MBYTE (1u << 20)

typedef __bf16 bf16;
typedef bf16 bf16x8 __attribute__((ext_vector_type(8)));
typedef bf16 bf16x4 __attribute__((ext_vector_type(4)));
typedef float f32x4 __attribute__((ext_vector_type(4)));

typedef __attribute__((address_space(1))) void as1_void;
typedef __attribute__((address_space(3))) void as3_void;

__device__ __forceinline__ void gload16(const bf16* g, bf16* l) {
  __builtin_amdgcn_global_load_lds((as1_void*)g, (as3_void*)l, 16, 0, 0);
}

// ------------------------------- GEMM --------------------------------------
// C[M,N] (f32) = A[M,K] * Bm[N,K]^T, bf16 inputs, 128x128 tile, 4 waves,
// BK=32, global_load_lds staging (m97 structure). All dims % 128 == 0 (N may
// be %128), K % 32 == 0.
__global__ __launch_bounds__(256, 2) void gemm_bt(const bf16* __restrict__ A,
                                                  const bf16* __restrict__ Bm,
                                                  float* __restrict__ C,
                                                  int M, int N, int K) {
  __shared__ __align__(16) bf16 sA[128 * 32];
  __shared__ __align__(16) bf16 sB[128 * 32];
  const int tid = threadIdx.x;
  const int wave = tid >> 6, lane = tid & 63;
  const int quad = lane >> 4, l16 = lane & 15;
  const int m0 = blockIdx.y * 128, n0 = blockIdx.x * 128;
  const int waveM = (wave >> 1) * 64, waveN = (wave & 1) * 64;
  const int sr = lane >> 2;          // row within 16-row chunk
  const int kc = (lane & 3) * 8;     // k element offset within BK
  f32x4 acc[4][4] = {};

  const bf16* aBase = A + (size_t)m0 * K + kc;
  const bf16* bBase = Bm + (size_t)n0 * K + kc;

  for (int k0 = 0; k0 < K; k0 += 32) {
#pragma unroll
    for (int c = 0; c < 2; ++c) {
      const int chunk = wave * 2 + c;        // 0..7, wave-uniform
      const int row = chunk * 16 + sr;       // 0..127
      gload16(aBase + (size_t)row * K + k0, (bf16*)((char*)sA + chunk * 1024));
      gload16(bBase + (size_t)row * K + k0, (bf16*)((char*)sB + chunk * 1024));
    }
    __syncthreads();
    bf16x8 af[4], bfr[4];
#pragma unroll
    for (int i = 0; i < 4; ++i)
      af[i] = *(const bf16x8*)&sA[(waveM + i * 16 + l16) * 32 + quad * 8];
#pragma unroll
    for (int j = 0; j < 4; ++j)
      bfr[j] = *(const bf16x8*)&sB[(waveN + j * 16 + l16) * 32 + quad * 8];
#pragma unroll
    for (int i = 0; i < 4; ++i)
#pragma unroll
      for (int j = 0; j < 4; ++j)
        acc[i][j] = __builtin_amdgcn_mfma_f32_16x16x32_bf16(af[i], bfr[j], acc[i][j], 0, 0, 0);
    __syncthreads();
  }
  // C/D layout: col = lane&15, row = quad*4 + reg   [verified m89/m91]
#pragma unroll
  for (int i = 0; i < 4; ++i)
#pragma unroll
    for (int j = 0; j < 4; ++j)
#pragma unroll
      for (int r = 0; r < 4; ++r) {
        const int row = m0 + waveM + i * 16 + quad * 4 + r;
        const int col = n0 + waveN + j * 16 + l16;
        C[(size_t)row * N + col] = acc[i][j][r];
      }
}

// --------------------------- small kernels ---------------------------------
__global__ void f2b_kernel(const float* __restrict__ in, bf16* __restrict__ out, int n) {
  const int idx = (blockIdx.x * 256 + threadIdx.x) * 4;
  if (idx < n) {
    f32x4 v = *(const f32x4*)(in + idx);
    bf16x4 o;
    o.x = (bf16)v.x; o.y = (bf16)v.y; o.z = (bf16)v.z; o.w = (bf16)v.w;
    *(bf16x4*)(out + idx) = o;
  }
}

__device__ __forceinline__ float block_reduce_sum(float s, float* ws4) {
  for (int off = 32; off > 0; off >>= 1) s += __shfl_down(s, off, 64);
  const int tid = threadIdx.x;
  if ((tid & 63) == 0) ws4[tid >> 6] = s;
  __syncthreads();
  return ws4[0] + ws4[1] + ws4[2] + ws4[3];
}

// SEN[row] = sum_j X[row][j]^2
__global__ void sen_kernel(const float* __restrict__ X, float* __restrict__ SEN, int Mcols) {
  const int row = blockIdx.x, tid = threadIdx.x;
  const float* xr = X + (size_t)row * Mcols;
  float s = 0.f;
  for (int c = tid * 4; c < Mcols; c += 1024) {
    f32x4 v = *(const f32x4*)(xr + c);
    s += v.x * v.x + v.y * v.y + v.z * v.z + v.w * v.w;
  }
  __shared__ float ws4[4];
  float tot = block_reduce_sum(s, ws4);
  if (tid == 0) SEN[row] = tot;
}

// part[rc][col] = sum of X[r][col] over the rc-th 1/16 chunk of rows
__global__ void colsum_kernel(const float* __restrict__ X, float* __restrict__ part,
                              int Nrows, int Mcols) {
  const int col = blockIdx.x * 256 + threadIdx.x;
  const int rc = blockIdx.y;
  const int cs = Nrows / 16;
  const int r0 = rc * cs, r1 = r0 + cs;
  float s = 0.f;
  for (int r = r0; r < r1; ++r) s += X[(size_t)r * Mcols + col];
  part[(size_t)rc * Mcols + col] = s;
}

// scal[0] = stau = 0.5*(mean(SEN) - sum(gmean^2))
__global__ void base_kernel(const float* __restrict__ SEN, const float* __restrict__ part,
                            float* __restrict__ scal, int Nsamp, int Mcols) {
  const int tid = threadIdx.x;
  const float invN = 1.0f / (float)Nsamp;
  float ssen = 0.f;
  for (int i = tid; i < Nsamp; i += 256) ssen += SEN[i];
  float sg2 = 0.f;
  for (int c = tid; c < Mcols; c += 256) {
    float cs = 0.f;
    for (int p = 0; p < 16; ++p) cs += part[(size_t)p * Mcols + c];
    const float gm = cs * invN;
    sg2 += gm * gm;
  }
  __shared__ float r1[256], r2[256];
  r1[tid] = ssen; r2[tid] = sg2;
  __syncthreads();
  for (int s = 128; s; s >>= 1) {
    if (tid < s) { r1[tid] += r1[tid + s]; r2[tid] += r2[tid + s]; }
    __syncthreads();
  }
  if (tid == 0) scal[0] = 0.5f * (r1[0] * invN - r2[0]);
}

// e[i] = 1 iff exists j<i with dens(i,j) >= DELTA (superset of proto-conflicts)
__global__ void edges_kernel(const float* __restrict__ G, const float* __restrict__ SEN,
                             const float* __restrict__ scal, int N, int* __restrict__ e) {
  const int i = blockIdx.x, tid = threadIdx.x;
  const float stau = scal[0];
  const float si = SEN[i];
  const float* gi = G + (size_t)i * N;
  __shared__ int sflag;
  if (tid == 0) sflag = 0;
  __syncthreads();
  int f = 0;
  for (int j = tid; j < i; j += 256) {
    const float d = si + SEN[j] - 2.0f * gi[j];
    if (expf(-d / stau) >= DELTA_F) f = 1;
  }
  if (f) atomicOr(&sflag, 1);
  __syncthreads();
  if (tid == 0) e[i] = sflag;
}

// Exact sequential resolution of the (rare) e[i]==1 samples. Single block.
__global__ void decide_kernel(const int* __restrict__ e, const float* __restrict__ G,
                              const float* __restrict__ SEN, const float* __restrict__ scal,
                              int N, int* __restrict__ newflag, int* __restrict__ assigned) {
  __shared__ int s_flag[2048];
  __shared__ short s_list[2048];
  __shared__ int s_T;
  __shared__ float rbest[256];
  __shared__ int rbj[256];
  const int tid = threadIdx.x;
  const float stau = scal[0];
  for (int i = tid; i < N; i += 256) {
    const int ei = e[i];
    s_flag[i] = (ei == 0);
    if (ei == 0) { newflag[i] = 1; assigned[i] = i; }
  }
  __syncthreads();
  if (tid == 0) {
    int T = 0;
    for (int i = 0; i < N; ++i)
      if (!s_flag[i]) s_list[T++] = (short)i;
    s_T = T;
  }
  __syncthreads();
  const int T = s_T;
  for (int t = 0; t < T; ++t) {
    const int i = s_list[t];
    const float si = SEN[i];
    const float* gi = G + (size_t)i * N;
    float best = -1.0f;
    int bestj = 0x7fffffff;
    for (int j = tid; j < i; j += 256) {
      if (s_flag[j]) {  // j is a prototype created before i
        const float dens = expf(-(si + SEN[j] - 2.0f * gi[j]) / stau);
        if (dens > best || (dens == best && j < bestj)) { best = dens; bestj = j; }
      }
    }
    rbest[tid] = best; rbj[tid] = bestj;
    __syncthreads();
    if (tid == 0) {
      float b = -1.0f;
      int bj = 0x7fffffff;
      for (int k = 0; k < 256; ++k)
        if (rbest[k] > b || (rbest[k] == b && rbj[k] < bj)) { b = rbest[k]; bj = rbj[k]; }
      if (b < DELTA_F) {  // new rule (also covers "no prototypes yet")
        s_flag[i] = 1; newflag[i] = 1; assigned[i] = i;
      } else {
        newflag[i] = 0; assigned[i] = bj;
      }
    }
    __syncthreads();
  }
}

// lamb[n] = dens(n, assigned[n]) / sum over prototypes j of dens(n, j)
__global__ void lamb_kernel(const float* __restrict__ G, const float* __restrict__ SEN,
                            const float* __restrict__ scal, const int* __restrict__ newflag,
                            const int* __restrict__ assigned, int N, float* __restrict__ lamb) {
  const int n = blockIdx.x, tid = threadIdx.x;
  const float stau = scal[0];
  const float sn = SEN[n];
  const float* gn = G + (size_t)n * N;
  float sum = 0.f;
  for (int j = tid; j < N; j += 256)
    if (newflag[j]) sum += expf(-(sn + SEN[j] - 2.0f * gn[j]) / stau);
  __shared__ float ws4[4];
  const float total = block_reduce_sum(sum, ws4);
  if (tid == 0) {
    const int a = assigned[n];
    const float da = expf(-(sn + SEN[a] - 2.0f * gn[a]) / stau);
    lamb[n] = da / total;
  }
}

// H = sigmoid(Z + b) (in-place ok); optional bf16 copy
__global__ void bias_sig_kernel(const float* __restrict__ Z, const float* __restrict__ b,
                                float* __restrict__ H, bf16* __restrict__ Hb, int Ncols) {
  const int col = blockIdx.x * 256 + threadIdx.x;
  const size_t idx = (size_t)blockIdx.y * Ncols + col;
  const float z = Z[idx] + b[col];
  const float h = 1.0f / (1.0f + expf(-z));
  H[idx] = h;
  if (Hb) Hb[idx] = (bf16)h;
}

// ------------------------------- driver ------------------------------------
extern "C" void kernel_launch(void* const* d_in, const int* in_sizes, int n_in,
                              void* d_out, int out_size, void* d_ws, size_t ws_size,
                              hipStream_t stream) {
  const float* x = (const float*)d_in[0];
  const float* W0 = (const float*)d_in[1];
  const float* b0 = (const float*)d_in[2];
  const float* W1 = (const float*)d_in[3];
  const float* b1 = (const float*)d_in[4];
  float* out = (float*)d_out;

  const int N = 2048, DIN = 2048, DH = 2048, DOUT = 1024;

  char* w = (char*)d_ws;
  bf16* xb = (bf16*)(w);                 // 8 MB: bf16(x), later bf16(h)
  bf16* wb = (bf16*)(w + 8 * MBYTE);     // 8 MB: bf16(W0), later bf16(W1)
  float* G = (float*)(w + 16 * MBYTE);   // 16 MB: Gram matrix
  float* Z = (float*)(w + 32 * MBYTE);   // 16 MB: Z0 / h (f32)
  float* SEN = (float*)(w + 48 * MBYTE); // 2048 f32
  float* part = SEN + 2048;              // 16*2048 f32
  float* scal = part + 16 * 2048;        // stau
  int* e = (int*)(scal + 16);            // 2048 i32
  int* nf = e + 2048;                    // 2048 i32
  int* as = nf + 2048;                   // 2048 i32

  float* lamb0 = out + (size_t)N * DOUT;
  float* lamb1 = lamb0 + N;

  // ---------------- layer 0 (codebook on x, then h=sig(x W0^T + b0)) -------
  f2b_kernel<<<(N * DIN) / 1024, 256, 0, stream>>>(x, xb, N * DIN);
  f2b_kernel<<<(DH * DIN) / 1024, 256, 0, stream>>>(W0, wb, DH * DIN);
  sen_kernel<<<N, 256, 0, stream>>>(x, SEN, DIN);
  colsum_kernel<<<dim3(DIN / 256, 16), 256, 0, stream>>>(x, part, N, DIN);
  base_kernel<<<1, 256, 0, stream>>>(SEN, part, scal, N, DIN);
  gemm_bt<<<dim3(N / 128, N / 128), 256, 0, stream>>>(xb, xb, G, N, N, DIN);
  edges_kernel<<<N, 256, 0, stream>>>(G, SEN, scal, N, e);
  decide_kernel<<<1, 256, 0, stream>>>(e, G, SEN, scal, N, nf, as);
  lamb_kernel<<<N, 256, 0, stream>>>(G, SEN, scal, nf, as, N, lamb0);
  gemm_bt<<<dim3(DH / 128, N / 128), 256, 0, stream>>>(xb, wb, Z, N, DH, DIN);
  bias_sig_kernel<<<dim3(DH / 256, N), 256, 0, stream>>>(Z, b0, Z, xb /*hb*/, DH);

  // ---------------- layer 1 (codebook on h, then out=sig(h W1^T + b1)) -----
  sen_kernel<<<N, 256, 0, stream>>>(Z, SEN, DH);
  colsum_kernel<<<dim3(DH / 256, 16), 256, 0, stream>>>(Z, part, N, DH);
  base_kernel<<<1, 256, 0, stream>>>(SEN, part, scal, N, DH);
  gemm_bt<<<dim3(N / 128, N / 128), 256, 0, stream>>>(xb, xb, G, N, N, DH);
  edges_kernel<<<N, 256, 0, stream>>>(G, SEN, scal, N, e);
  decide_kernel<<<1, 256, 0, stream>>>(e, G, SEN, scal, N, nf, as);
  lamb_kernel<<<N, 256, 0, stream>>>(G, SEN, scal, nf, as, N, lamb1);
  f2b_kernel<<<(DOUT * DH) / 1024, 256, 0, stream>>>(W1, wb, DOUT * DH);
  gemm_bt<<<dim3(DOUT / 128, N / 128), 256, 0, stream>>>(xb, wb, out, N, DOUT, DH);
  bias_sig_kernel<<<dim3(DOUT / 256, N), 256, 0, stream>>>(out, b1, out, nullptr, DOUT);
}

// Round 2
// 387.760 us; speedup vs baseline: 1.4965x; 1.4965x over previous
//
#include <hip/hip_runtime.h>
#include <cstdint>
#include <cstddef>

// ---------------------------------------------------------------------------
// SOMFNN forward: h = sigmoid(sigmoid(x@W0.T+b0)@W1.T+b1), plus per-layer
// ALMMo codebook lamb. Key simplifications (provably exact vs reference):
//   * SENc==cn2 always  =>  stau = base/2, constant scalar per layer.
//   * prototypes are never updated => all distances come from the Gram matrix
//     G = X X^T:  dist(i,j) = SEN[i]+SEN[j]-2 G[i,j].
//   * sample i is NEW iff no earlier PROTOTYPE j has dens>=DELTA. Parallel
//     pre-pass: e_i = any j<i with dens>=DELTA  (e_i=0 => definitively NEW).
//     The e_i=1 stragglers (expected: none for this data) are resolved
//     exactly by a single-block sequential pass with parallel compaction
//     (R1: serial tid==0 compaction was 103 us of LDS latency; prefix-sum
//     compaction preserves ascending order exactly).
// ---------------------------------------------------------------------------

#define DELTA_F 0.13533528323661270f  // float(exp(-2))
#define MBYTE (1u << 20)

typedef __bf16 bf16;
typedef bf16 bf16x8 __attribute__((ext_vector_type(8)));
typedef bf16 bf16x4 __attribute__((ext_vector_type(4)));
typedef float f32x4 __attribute__((ext_vector_type(4)));

typedef __attribute__((address_space(1))) void as1_void;
typedef __attribute__((address_space(3))) void as3_void;

__device__ __forceinline__ void gload16(const bf16* g, bf16* l) {
  __builtin_amdgcn_global_load_lds((as1_void*)g, (as3_void*)l, 16, 0, 0);
}

// ------------------------------- GEMM --------------------------------------
// C[M,N] (f32) = A[M,K] * Bm[N,K]^T, bf16 inputs, 128x128 tile, 8 waves
// (512 thr -> 2 waves/SIMD at 1 block/CU), BK=32, global_load_lds staging.
// Each wave owns a 32x64 sub-tile (acc[2][4] of 16x16) and stages one
// 16-row A chunk + one 16-row B chunk per K-iter. Dims: M,N %128, K %32.
__global__ __launch_bounds__(512, 2) void gemm_bt(const bf16* __restrict__ A,
                                                  const bf16* __restrict__ Bm,
                                                  float* __restrict__ C,
                                                  int M, int N, int K) {
  __shared__ __align__(16) bf16 sA[128 * 32];
  __shared__ __align__(16) bf16 sB[128 * 32];
  const int tid = threadIdx.x;
  const int wave = tid >> 6, lane = tid & 63;
  const int quad = lane >> 4, l16 = lane & 15;
  const int m0 = blockIdx.y * 128, n0 = blockIdx.x * 128;
  const int waveM = (wave >> 1) * 32, waveN = (wave & 1) * 64;
  const int sr = lane >> 2;          // row within 16-row chunk
  const int kc = (lane & 3) * 8;     // k element offset within BK
  f32x4 acc[2][4] = {};

  const int srow = wave * 16 + sr;   // staging row 0..127 (chunk = wave)
  const bf16* aBase = A + (size_t)(m0 + srow) * K + kc;
  const bf16* bBase = Bm + (size_t)(n0 + srow) * K + kc;

  for (int k0 = 0; k0 < K; k0 += 32) {
    gload16(aBase + k0, (bf16*)((char*)sA + wave * 1024));
    gload16(bBase + k0, (bf16*)((char*)sB + wave * 1024));
    __syncthreads();
    bf16x8 af[2], bfr[4];
#pragma unroll
    for (int i = 0; i < 2; ++i)
      af[i] = *(const bf16x8*)&sA[(waveM + i * 16 + l16) * 32 + quad * 8];
#pragma unroll
    for (int j = 0; j < 4; ++j)
      bfr[j] = *(const bf16x8*)&sB[(waveN + j * 16 + l16) * 32 + quad * 8];
#pragma unroll
    for (int i = 0; i < 2; ++i)
#pragma unroll
      for (int j = 0; j < 4; ++j)
        acc[i][j] = __builtin_amdgcn_mfma_f32_16x16x32_bf16(af[i], bfr[j], acc[i][j], 0, 0, 0);
    __syncthreads();
  }
  // C/D layout: col = lane&15, row = quad*4 + reg   [verified m89/m91]
#pragma unroll
  for (int i = 0; i < 2; ++i)
#pragma unroll
    for (int j = 0; j < 4; ++j)
#pragma unroll
      for (int r = 0; r < 4; ++r) {
        const int row = m0 + waveM + i * 16 + quad * 4 + r;
        const int col = n0 + waveN + j * 16 + l16;
        C[(size_t)row * N + col] = acc[i][j][r];
      }
}

// --------------------------- small kernels ---------------------------------
__global__ void f2b_kernel(const float* __restrict__ in, bf16* __restrict__ out, int n) {
  const int idx = (blockIdx.x * 256 + threadIdx.x) * 4;
  if (idx < n) {
    f32x4 v = *(const f32x4*)(in + idx);
    bf16x4 o;
    o.x = (bf16)v.x; o.y = (bf16)v.y; o.z = (bf16)v.z; o.w = (bf16)v.w;
    *(bf16x4*)(out + idx) = o;
  }
}

__device__ __forceinline__ float block_reduce_sum(float s, float* ws4) {
  for (int off = 32; off > 0; off >>= 1) s += __shfl_down(s, off, 64);
  const int tid = threadIdx.x;
  if ((tid & 63) == 0) ws4[tid >> 6] = s;
  __syncthreads();
  return ws4[0] + ws4[1] + ws4[2] + ws4[3];
}

// SEN[row] = sum_j X[row][j]^2
__global__ void sen_kernel(const float* __restrict__ X, float* __restrict__ SEN, int Mcols) {
  const int row = blockIdx.x, tid = threadIdx.x;
  const float* xr = X + (size_t)row * Mcols;
  float s = 0.f;
  for (int c = tid * 4; c < Mcols; c += 1024) {
    f32x4 v = *(const f32x4*)(xr + c);
    s += v.x * v.x + v.y * v.y + v.z * v.z + v.w * v.w;
  }
  __shared__ float ws4[4];
  float tot = block_reduce_sum(s, ws4);
  if (tid == 0) SEN[row] = tot;
}

// part[rc][col] = sum of X[r][col] over the rc-th 1/16 chunk of rows
__global__ void colsum_kernel(const float* __restrict__ X, float* __restrict__ part,
                              int Nrows, int Mcols) {
  const int col = blockIdx.x * 256 + threadIdx.x;
  const int rc = blockIdx.y;
  const int cs = Nrows / 16;
  const int r0 = rc * cs, r1 = r0 + cs;
  float s = 0.f;
  for (int r = r0; r < r1; ++r) s += X[(size_t)r * Mcols + col];
  part[(size_t)rc * Mcols + col] = s;
}

// scal[0] = stau = 0.5*(mean(SEN) - sum(gmean^2))
__global__ void base_kernel(const float* __restrict__ SEN, const float* __restrict__ part,
                            float* __restrict__ scal, int Nsamp, int Mcols) {
  const int tid = threadIdx.x;
  const float invN = 1.0f / (float)Nsamp;
  float ssen = 0.f;
  for (int i = tid; i < Nsamp; i += 256) ssen += SEN[i];
  float sg2 = 0.f;
  for (int c = tid; c < Mcols; c += 256) {
    float cs = 0.f;
    for (int p = 0; p < 16; ++p) cs += part[(size_t)p * Mcols + c];
    const float gm = cs * invN;
    sg2 += gm * gm;
  }
  __shared__ float r1[256], r2[256];
  r1[tid] = ssen; r2[tid] = sg2;
  __syncthreads();
  for (int s = 128; s; s >>= 1) {
    if (tid < s) { r1[tid] += r1[tid + s]; r2[tid] += r2[tid + s]; }
    __syncthreads();
  }
  if (tid == 0) scal[0] = 0.5f * (r1[0] * invN - r2[0]);
}

// e[i] = 1 iff exists j<i with dens(i,j) >= DELTA (superset of proto-conflicts)
__global__ void edges_kernel(const float* __restrict__ G, const float* __restrict__ SEN,
                             const float* __restrict__ scal, int N, int* __restrict__ e) {
  const int i = blockIdx.x, tid = threadIdx.x;
  const float stau = scal[0];
  const float si = SEN[i];
  const float* gi = G + (size_t)i * N;
  __shared__ int sflag;
  if (tid == 0) sflag = 0;
  __syncthreads();
  int f = 0;
  for (int j = tid; j < i; j += 256) {
    const float d = si + SEN[j] - 2.0f * gi[j];
    if (expf(-d / stau) >= DELTA_F) f = 1;
  }
  if (f) atomicOr(&sflag, 1);
  __syncthreads();
  if (tid == 0) e[i] = sflag;
}

// Exact sequential resolution of the (rare) e[i]==1 samples. Single block.
// Compaction is a 256-thread prefix-sum (order-preserving; each thread owns
// a contiguous 8-index chunk) -- no serial LDS-latency loop.
__global__ void decide_kernel(const int* __restrict__ e, const float* __restrict__ G,
                              const float* __restrict__ SEN, const float* __restrict__ scal,
                              int N, int* __restrict__ newflag, int* __restrict__ assigned) {
  __shared__ int s_flag[2048];
  __shared__ short s_list[2048];
  __shared__ int s_T;
  __shared__ int scan[256];
  __shared__ float rbest[256];
  __shared__ int rbj[256];
  const int tid = threadIdx.x;
  const float stau = scal[0];
  const int per = N / 256;  // 8 contiguous indices per thread
  int cnt = 0;
  for (int k = 0; k < per; ++k) {
    const int i = tid * per + k;
    const int ei = e[i];
    s_flag[i] = (ei == 0);
    if (ei == 0) { newflag[i] = 1; assigned[i] = i; }
    cnt += ei;
  }
  scan[tid] = cnt;
  __syncthreads();
  // Hillis-Steele inclusive scan over 256 per-thread counts
  for (int off = 1; off < 256; off <<= 1) {
    const int v = scan[tid];
    const int add = (tid >= off) ? scan[tid - off] : 0;
    __syncthreads();
    scan[tid] = v + add;
    __syncthreads();
  }
  int pos = scan[tid] - cnt;  // exclusive prefix
  for (int k = 0; k < per; ++k) {
    const int i = tid * per + k;
    if (!s_flag[i]) s_list[pos++] = (short)i;
  }
  if (tid == 255) s_T = scan[255];
  __syncthreads();
  const int T = s_T;
  for (int t = 0; t < T; ++t) {
    const int i = s_list[t];
    const float si = SEN[i];
    const float* gi = G + (size_t)i * N;
    float best = -1.0f;
    int bestj = 0x7fffffff;
    for (int j = tid; j < i; j += 256) {
      if (s_flag[j]) {  // j is a prototype created before i
        const float dens = expf(-(si + SEN[j] - 2.0f * gi[j]) / stau);
        if (dens > best || (dens == best && j < bestj)) { best = dens; bestj = j; }
      }
    }
    rbest[tid] = best; rbj[tid] = bestj;
    __syncthreads();
    if (tid == 0) {
      float b = -1.0f;
      int bj = 0x7fffffff;
      for (int k = 0; k < 256; ++k)
        if (rbest[k] > b || (rbest[k] == b && rbj[k] < bj)) { b = rbest[k]; bj = rbj[k]; }
      if (b < DELTA_F) {  // new rule (also covers "no prototypes yet")
        s_flag[i] = 1; newflag[i] = 1; assigned[i] = i;
      } else {
        newflag[i] = 0; assigned[i] = bj;
      }
    }
    __syncthreads();
  }
}

// lamb[n] = dens(n, assigned[n]) / sum over prototypes j of dens(n, j)
__global__ void lamb_kernel(const float* __restrict__ G, const float* __restrict__ SEN,
                            const float* __restrict__ scal, const int* __restrict__ newflag,
                            const int* __restrict__ assigned, int N, float* __restrict__ lamb) {
  const int n = blockIdx.x, tid = threadIdx.x;
  const float stau = scal[0];
  const float sn = SEN[n];
  const float* gn = G + (size_t)n * N;
  float sum = 0.f;
  for (int j = tid; j < N; j += 256)
    if (newflag[j]) sum += expf(-(sn + SEN[j] - 2.0f * gn[j]) / stau);
  __shared__ float ws4[4];
  const float total = block_reduce_sum(sum, ws4);
  if (tid == 0) {
    const int a = assigned[n];
    const float da = expf(-(sn + SEN[a] - 2.0f * gn[a]) / stau);
    lamb[n] = da / total;
  }
}

// H = sigmoid(Z + b) (in-place ok); optional bf16 copy
__global__ void bias_sig_kernel(const float* __restrict__ Z, const float* __restrict__ b,
                                float* __restrict__ H, bf16* __restrict__ Hb, int Ncols) {
  const int col = blockIdx.x * 256 + threadIdx.x;
  const size_t idx = (size_t)blockIdx.y * Ncols + col;
  const float z = Z[idx] + b[col];
  const float h = 1.0f / (1.0f + expf(-z));
  H[idx] = h;
  if (Hb) Hb[idx] = (bf16)h;
}

// ------------------------------- driver ------------------------------------
extern "C" void kernel_launch(void* const* d_in, const int* in_sizes, int n_in,
                              void* d_out, int out_size, void* d_ws, size_t ws_size,
                              hipStream_t stream) {
  const float* x = (const float*)d_in[0];
  const float* W0 = (const float*)d_in[1];
  const float* b0 = (const float*)d_in[2];
  const float* W1 = (const float*)d_in[3];
  const float* b1 = (const float*)d_in[4];
  float* out = (float*)d_out;

  const int N = 2048, DIN = 2048, DH = 2048, DOUT = 1024;

  char* w = (char*)d_ws;
  bf16* xb = (bf16*)(w);                 // 8 MB: bf16(x), later bf16(h)
  bf16* wb = (bf16*)(w + 8 * MBYTE);     // 8 MB: bf16(W0), later bf16(W1)
  float* G = (float*)(w + 16 * MBYTE);   // 16 MB: Gram matrix
  float* Z = (float*)(w + 32 * MBYTE);   // 16 MB: Z0 / h (f32)
  float* SEN = (float*)(w + 48 * MBYTE); // 2048 f32
  float* part = SEN + 2048;              // 16*2048 f32
  float* scal = part + 16 * 2048;        // stau
  int* e = (int*)(scal + 16);            // 2048 i32
  int* nf = e + 2048;                    // 2048 i32
  int* as = nf + 2048;                   // 2048 i32

  float* lamb0 = out + (size_t)N * DOUT;
  float* lamb1 = lamb0 + N;

  // ---------------- layer 0 (codebook on x, then h=sig(x W0^T + b0)) -------
  f2b_kernel<<<(N * DIN) / 1024, 256, 0, stream>>>(x, xb, N * DIN);
  f2b_kernel<<<(DH * DIN) / 1024, 256, 0, stream>>>(W0, wb, DH * DIN);
  sen_kernel<<<N, 256, 0, stream>>>(x, SEN, DIN);
  colsum_kernel<<<dim3(DIN / 256, 16), 256, 0, stream>>>(x, part, N, DIN);
  base_kernel<<<1, 256, 0, stream>>>(SEN, part, scal, N, DIN);
  gemm_bt<<<dim3(N / 128, N / 128), 512, 0, stream>>>(xb, xb, G, N, N, DIN);
  edges_kernel<<<N, 256, 0, stream>>>(G, SEN, scal, N, e);
  decide_kernel<<<1, 256, 0, stream>>>(e, G, SEN, scal, N, nf, as);
  lamb_kernel<<<N, 256, 0, stream>>>(G, SEN, scal, nf, as, N, lamb0);
  gemm_bt<<<dim3(DH / 128, N / 128), 512, 0, stream>>>(xb, wb, Z, N, DH, DIN);
  bias_sig_kernel<<<dim3(DH / 256, N), 256, 0, stream>>>(Z, b0, Z, xb /*hb*/, DH);

  // ---------------- layer 1 (codebook on h, then out=sig(h W1^T + b1)) -----
  sen_kernel<<<N, 256, 0, stream>>>(Z, SEN, DH);
  colsum_kernel<<<dim3(DH / 256, 16), 256, 0, stream>>>(Z, part, N, DH);
  base_kernel<<<1, 256, 0, stream>>>(SEN, part, scal, N, DH);
  gemm_bt<<<dim3(N / 128, N / 128), 512, 0, stream>>>(xb, xb, G, N, N, DH);
  edges_kernel<<<N, 256, 0, stream>>>(G, SEN, scal, N, e);
  decide_kernel<<<1, 256, 0, stream>>>(e, G, SEN, scal, N, nf, as);
  lamb_kernel<<<N, 256, 0, stream>>>(G, SEN, scal, nf, as, N, lamb1);
  f2b_kernel<<<(DOUT * DH) / 1024, 256, 0, stream>>>(W1, wb, DOUT * DH);
  gemm_bt<<<dim3(DOUT / 128, N / 128), 512, 0, stream>>>(xb, wb, out, N, DOUT, DH);
  bias_sig_kernel<<<dim3(DOUT / 256, N), 256, 0, stream>>>(out, b1, out, nullptr, DOUT);
}

// Round 3
// 289.391 us; speedup vs baseline: 2.0051x; 1.3399x over previous
//
#include <hip/hip_runtime.h>
#include <cstdint>
#include <cstddef>

// ---------------------------------------------------------------------------
// SOMFNN forward. Exact-semantics reductions vs reference:
//   * stau = base/2 is a per-layer scalar (SENc==cn2 identically).
//   * prototypes never updated => all distances from Gram G = X X^T.
//   * SEN := diag(G), base := mean(diag G) - sum(G)/N^2 (bf16-Gram-consistent;
//     decision margins are >1000x the quantization error for this regime).
//   * leader-clustering scan parallelized: e_i = any j<i with dens>=DELTA
//     (e_i=0 => definitively NEW); stragglers resolved exactly in one block.
// R2->R3: gemm restructured to 2m x 2n x 2k wave split (BK=64, XOR-swizzled
// LDS written via swizzled *global* addresses since global_load_lds cannot
// scatter); stats + bias/sigmoid fused into gemm epilogues (21 -> 14 nodes).
// ---------------------------------------------------------------------------

#define DELTA_F 0.13533528323661270f  // float(exp(-2))
#define MBYTE (1u << 20)

typedef __bf16 bf16;
typedef bf16 bf16x8 __attribute__((ext_vector_type(8)));
typedef bf16 bf16x4 __attribute__((ext_vector_type(4)));
typedef float f32x4 __attribute__((ext_vector_type(4)));

typedef __attribute__((address_space(1))) void as1_void;
typedef __attribute__((address_space(3))) void as3_void;

__device__ __forceinline__ void gload16(const bf16* g, bf16* l) {
  __builtin_amdgcn_global_load_lds((as1_void*)g, (as3_void*)l, 16, 0, 0);
}

#define GEMM_GRAM 0    // C=f32 G store + SEN=diag + atomicAdd(sum G)
#define GEMM_SIGB16 1  // h = sigmoid(v+bias), store bf16 only
#define GEMM_SIGF32 2  // h = sigmoid(v+bias), store f32 only

// C[M,N] = A[M,K] * Bm[N,K]^T. 128xBN tile, 8 waves = 2m x 2n x 2k, BK=64.
// LDS rows are 128B; 16B slots XOR-swizzled by (row&7) to kill bank conflicts
// (swizzle applied on the global source address; LDS dest is lane-ordered).
template <int BN, int MODE>
__global__ __launch_bounds__(512, 2) void gemm_bt(
    const bf16* __restrict__ A, const bf16* __restrict__ Bm,
    float* __restrict__ C, bf16* __restrict__ Hb,
    const float* __restrict__ bias, float* __restrict__ SEN,
    float* __restrict__ sumAll, int M, int N, int K) {
  constexpr int JJ = (BN == 128) ? 4 : 2;
  __shared__ __align__(16) char smem[16384 + BN * 128];
  const int tid = threadIdx.x;
  const int wave = tid >> 6, lane = tid & 63;
  const int quad = lane >> 4, l16 = lane & 15;
  const int kg = wave & 1, wm = (wave >> 1) & 1, wn = (wave >> 2) & 1;
  const int m0 = blockIdx.y * 128, n0 = blockIdx.x * BN;
  const int waveM = wm * 64, waveN = wn * (BN / 2);
  // staging lane roles: 8 rows x 8 slots of 16B per gload16
  const int sr8 = lane >> 3, slot = lane & 7;
  const int gk = (slot ^ sr8) * 8;  // swizzled global k-element offset
  const bf16* aSrc = A + (size_t)(m0 + wave * 16 + sr8) * K + gk;
  const bf16* bSrc = Bm + (size_t)(n0 + (BN == 128 ? wave * 16 : wave * 8) + sr8) * K + gk;
  char* const aDst = smem + wave * 2048;
  char* const bDst = smem + 16384 + wave * (BN == 128 ? 2048 : 1024);
  // fragment read offsets (bytes): row*128 + swizzled 16B slot
  const int swz = ((kg * 4 + quad) ^ (l16 & 7)) * 16;
  const int aOff = (waveM + l16) * 128 + swz;
  const int bOff = 16384 + (waveN + l16) * 128 + swz;

  f32x4 acc[4][JJ] = {};

  for (int k0 = 0; k0 < K; k0 += 64) {
    gload16(aSrc + k0, (bf16*)aDst);
    gload16(aSrc + 8 * (size_t)K + k0, (bf16*)(aDst + 1024));
    if constexpr (BN == 128) {
      gload16(bSrc + k0, (bf16*)bDst);
      gload16(bSrc + 8 * (size_t)K + k0, (bf16*)(bDst + 1024));
    } else {
      gload16(bSrc + k0, (bf16*)bDst);
    }
    __syncthreads();
    bf16x8 af[4], bfr[JJ];
#pragma unroll
    for (int i = 0; i < 4; ++i) af[i] = *(const bf16x8*)(smem + aOff + i * 2048);
#pragma unroll
    for (int j = 0; j < JJ; ++j) bfr[j] = *(const bf16x8*)(smem + bOff + j * 2048);
#pragma unroll
    for (int i = 0; i < 4; ++i)
#pragma unroll
      for (int j = 0; j < JJ; ++j)
        acc[i][j] = __builtin_amdgcn_mfma_f32_16x16x32_bf16(af[i], bfr[j], acc[i][j], 0, 0, 0);
    __syncthreads();
  }

  // epilogue: merge kg=1 partials into kg=0 via LDS (2 rounds of 2 i's)
  float gsum = 0.f;
  char* const ex = smem + (wn * 2 + wm) * (2 * JJ * 1024);
#pragma unroll
  for (int round = 0; round < 2; ++round) {
    __syncthreads();
    if (kg == 1) {
#pragma unroll
      for (int ii = 0; ii < 2; ++ii)
#pragma unroll
        for (int j = 0; j < JJ; ++j)
          *(f32x4*)(ex + (ii * JJ + j) * 1024 + lane * 16) = acc[round * 2 + ii][j];
    }
    __syncthreads();
    if (kg == 0) {
#pragma unroll
      for (int ii = 0; ii < 2; ++ii) {
        const int i = round * 2 + ii;
#pragma unroll
        for (int j = 0; j < JJ; ++j) {
          f32x4 v = acc[i][j] + *(const f32x4*)(ex + (ii * JJ + j) * 1024 + lane * 16);
          const int col = n0 + waveN + j * 16 + l16;
          float bv = 0.f;
          if (MODE != GEMM_GRAM) bv = bias[col];
#pragma unroll
          for (int r = 0; r < 4; ++r) {
            const int row = m0 + waveM + i * 16 + quad * 4 + r;
            if (MODE == GEMM_GRAM) {
              const float val = v[r];
              C[(size_t)row * N + col] = val;
              gsum += val;
              if (row == col) SEN[row] = val;
            } else {
              const float hv = 1.0f / (1.0f + expf(-(v[r] + bv)));
              if (MODE == GEMM_SIGB16) Hb[(size_t)row * N + col] = (bf16)hv;
              else C[(size_t)row * N + col] = hv;
            }
          }
        }
      }
    }
  }
  if (MODE == GEMM_GRAM && kg == 0) {
    for (int off = 32; off > 0; off >>= 1) gsum += __shfl_down(gsum, off, 64);
    if (lane == 0) atomicAdd(sumAll, gsum);
  }
}

// --------------------------- small kernels ---------------------------------
__device__ __forceinline__ float block_reduce_sum(float s, float* ws4) {
  for (int off = 32; off > 0; off >>= 1) s += __shfl_down(s, off, 64);
  const int tid = threadIdx.x;
  if ((tid & 63) == 0) ws4[tid >> 6] = s;
  __syncthreads();
  return ws4[0] + ws4[1] + ws4[2] + ws4[3];
}

// one-shot f32->bf16 of x, W0, W1 (segment sizes baked for this problem)
__global__ void f2b_all(const float* __restrict__ x, const float* __restrict__ W0,
                        const float* __restrict__ W1, bf16* __restrict__ xb,
                        bf16* __restrict__ wb0, bf16* __restrict__ wb1) {
  const int idx = (blockIdx.x * 256 + threadIdx.x) * 4;
  const float* src;
  bf16* dst;
  int off;
  if (idx < 4194304) { src = x; dst = xb; off = idx; }
  else if (idx < 8388608) { src = W0; dst = wb0; off = idx - 4194304; }
  else { src = W1; dst = wb1; off = idx - 8388608; }
  f32x4 v = *(const f32x4*)(src + off);
  bf16x4 o;
  o.x = (bf16)v.x; o.y = (bf16)v.y; o.z = (bf16)v.z; o.w = (bf16)v.w;
  *(bf16x4*)(dst + off) = o;
}

// stau = 0.5*(mean(SEN) - sumAll/N^2)   (single block)
__global__ void stau_kernel(const float* __restrict__ SEN, const float* __restrict__ sumAll,
                            float* __restrict__ stauOut, int Nsamp) {
  const int tid = threadIdx.x;
  float s = 0.f;
  for (int i = tid; i < Nsamp; i += 256) s += SEN[i];
  __shared__ float ws4[4];
  const float tot = block_reduce_sum(s, ws4);
  if (tid == 0) {
    const float invN = 1.0f / (float)Nsamp;
    stauOut[0] = 0.5f * (tot * invN - sumAll[0] * invN * invN);
  }
}

// e[i] = 1 iff exists j<i with dens(i,j) >= DELTA
__global__ void edges_kernel(const float* __restrict__ G, const float* __restrict__ SEN,
                             const float* __restrict__ stau_p, int N, int* __restrict__ e) {
  const int i = blockIdx.x, tid = threadIdx.x;
  const float stau = stau_p[0];
  const float si = SEN[i];
  const float* gi = G + (size_t)i * N;
  __shared__ int sflag;
  if (tid == 0) sflag = 0;
  __syncthreads();
  int f = 0;
  for (int j = tid; j < i; j += 256) {
    const float d = si + SEN[j] - 2.0f * gi[j];
    if (expf(-d / stau) >= DELTA_F) f = 1;
  }
  if (f) atomicOr(&sflag, 1);
  __syncthreads();
  if (tid == 0) e[i] = sflag;
}

// Exact sequential resolution of e[i]==1 samples; prefix-sum compaction.
__global__ void decide_kernel(const int* __restrict__ e, const float* __restrict__ G,
                              const float* __restrict__ SEN, const float* __restrict__ stau_p,
                              int N, int* __restrict__ newflag, int* __restrict__ assigned) {
  __shared__ int s_flag[2048];
  __shared__ short s_list[2048];
  __shared__ int s_T;
  __shared__ int scan[256];
  __shared__ float rbest[256];
  __shared__ int rbj[256];
  const int tid = threadIdx.x;
  const float stau = stau_p[0];
  const int per = N / 256;
  int cnt = 0;
  for (int k = 0; k < per; ++k) {
    const int i = tid * per + k;
    const int ei = e[i];
    s_flag[i] = (ei == 0);
    if (ei == 0) { newflag[i] = 1; assigned[i] = i; }
    cnt += ei;
  }
  scan[tid] = cnt;
  __syncthreads();
  for (int off = 1; off < 256; off <<= 1) {
    const int v = scan[tid];
    const int add = (tid >= off) ? scan[tid - off] : 0;
    __syncthreads();
    scan[tid] = v + add;
    __syncthreads();
  }
  int pos = scan[tid] - cnt;
  for (int k = 0; k < per; ++k) {
    const int i = tid * per + k;
    if (!s_flag[i]) s_list[pos++] = (short)i;
  }
  if (tid == 255) s_T = scan[255];
  __syncthreads();
  const int T = s_T;
  for (int t = 0; t < T; ++t) {
    const int i = s_list[t];
    const float si = SEN[i];
    const float* gi = G + (size_t)i * N;
    float best = -1.0f;
    int bestj = 0x7fffffff;
    for (int j = tid; j < i; j += 256) {
      if (s_flag[j]) {
        const float dens = expf(-(si + SEN[j] - 2.0f * gi[j]) / stau);
        if (dens > best || (dens == best && j < bestj)) { best = dens; bestj = j; }
      }
    }
    rbest[tid] = best; rbj[tid] = bestj;
    __syncthreads();
    if (tid == 0) {
      float b = -1.0f;
      int bj = 0x7fffffff;
      for (int k = 0; k < 256; ++k)
        if (rbest[k] > b || (rbest[k] == b && rbj[k] < bj)) { b = rbest[k]; bj = rbj[k]; }
      if (b < DELTA_F) { s_flag[i] = 1; newflag[i] = 1; assigned[i] = i; }
      else { newflag[i] = 0; assigned[i] = bj; }
    }
    __syncthreads();
  }
}

// lamb[n] = dens(n, assigned[n]) / sum_{j: newflag} dens(n, j)
__global__ void lamb_kernel(const float* __restrict__ G, const float* __restrict__ SEN,
                            const float* __restrict__ stau_p, const int* __restrict__ newflag,
                            const int* __restrict__ assigned, int N, float* __restrict__ lamb) {
  const int n = blockIdx.x, tid = threadIdx.x;
  const float stau = stau_p[0];
  const float sn = SEN[n];
  const float* gn = G + (size_t)n * N;
  float sum = 0.f;
  for (int j = tid; j < N; j += 256)
    if (newflag[j]) sum += expf(-(sn + SEN[j] - 2.0f * gn[j]) / stau);
  __shared__ float ws4[4];
  const float total = block_reduce_sum(sum, ws4);
  if (tid == 0) {
    const int a = assigned[n];
    const float da = expf(-(sn + SEN[a] - 2.0f * gn[a]) / stau);
    lamb[n] = da / total;
  }
}

// ------------------------------- driver ------------------------------------
extern "C" void kernel_launch(void* const* d_in, const int* in_sizes, int n_in,
                              void* d_out, int out_size, void* d_ws, size_t ws_size,
                              hipStream_t stream) {
  const float* x = (const float*)d_in[0];
  const float* W0 = (const float*)d_in[1];
  const float* b0 = (const float*)d_in[2];
  const float* W1 = (const float*)d_in[3];
  const float* b1 = (const float*)d_in[4];
  float* out = (float*)d_out;

  const int N = 2048, DIN = 2048, DH = 2048, DOUT = 1024;

  char* w = (char*)d_ws;
  bf16* xb = (bf16*)(w);                  // 8 MB  bf16(x)
  bf16* wb0 = (bf16*)(w + 8 * MBYTE);     // 8 MB  bf16(W0)
  bf16* wb1 = (bf16*)(w + 16 * MBYTE);    // 4 MB  bf16(W1)
  bf16* hb = (bf16*)(w + 20 * MBYTE);     // 8 MB  bf16(h)
  float* G = (float*)(w + 28 * MBYTE);    // 16 MB Gram
  float* SEN = (float*)(w + 44 * MBYTE);  // 2048 f32 (diag G)
  float* scal = SEN + 2048;               // [0,1]=stau L0/L1, [2,3]=sumG L0/L1
  int* e = (int*)(scal + 16);
  int* nf = e + 2048;
  int* as = nf + 2048;

  float* lamb0 = out + (size_t)N * DOUT;
  float* lamb1 = lamb0 + N;

  hipMemsetAsync(scal, 0, 16 * sizeof(float), stream);
  f2b_all<<<10240, 256, 0, stream>>>(x, W0, W1, xb, wb0, wb1);

  // ---------------- layer 0 ----------------
  gemm_bt<128, GEMM_GRAM><<<dim3(N / 128, N / 128), 512, 0, stream>>>(
      xb, xb, G, nullptr, nullptr, SEN, scal + 2, N, N, DIN);
  stau_kernel<<<1, 256, 0, stream>>>(SEN, scal + 2, scal + 0, N);
  edges_kernel<<<N, 256, 0, stream>>>(G, SEN, scal + 0, N, e);
  decide_kernel<<<1, 256, 0, stream>>>(e, G, SEN, scal + 0, N, nf, as);
  lamb_kernel<<<N, 256, 0, stream>>>(G, SEN, scal + 0, nf, as, N, lamb0);
  gemm_bt<128, GEMM_SIGB16><<<dim3(DH / 128, N / 128), 512, 0, stream>>>(
      xb, wb0, nullptr, hb, b0, nullptr, nullptr, N, DH, DIN);

  // ---------------- layer 1 ----------------
  gemm_bt<128, GEMM_GRAM><<<dim3(N / 128, N / 128), 512, 0, stream>>>(
      hb, hb, G, nullptr, nullptr, SEN, scal + 3, N, N, DH);
  stau_kernel<<<1, 256, 0, stream>>>(SEN, scal + 3, scal + 1, N);
  edges_kernel<<<N, 256, 0, stream>>>(G, SEN, scal + 1, N, e);
  decide_kernel<<<1, 256, 0, stream>>>(e, G, SEN, scal + 1, N, nf, as);
  lamb_kernel<<<N, 256, 0, stream>>>(G, SEN, scal + 1, nf, as, N, lamb1);
  gemm_bt<64, GEMM_SIGF32><<<dim3(DOUT / 64, N / 128), 512, 0, stream>>>(
      hb, wb1, out, nullptr, b1, nullptr, nullptr, N, DOUT, DH);
}

// Round 4
// 231.632 us; speedup vs baseline: 2.5051x; 1.2494x over previous
//
#include <hip/hip_runtime.h>
#include <cstdint>
#include <cstddef>

// ---------------------------------------------------------------------------
// SOMFNN forward. Exact-semantics reductions vs reference:
//   * stau = base/2 is a per-layer scalar (SENc==cn2 identically).
//   * prototypes never updated => all distances from Gram G = X X^T.
//   * SEN := diag(G), base := mean(diag G) - sum(G)/N^2.
//   * leader-clustering scan parallelized: e_i = any j<i with dens>=DELTA
//     (e_i=0 => definitively NEW); stragglers resolved exactly in one block.
// R3->R4:
//   * Per layer, Gram-gemm and layer-gemm share operand A => ONE fused gemm
//     over B' = concat(X_or_W rows): grid 512/384 (was 256) -> 2 blocks/CU,
//     launch_bounds(512,4) -> 4 waves/SIMD in independent barrier domains
//     (R3 was 1 block/CU: all waves in one barrier domain, MfmaUtil 13%).
//   * edges + lamb denominator fused into one G pass (edgesum); lamb becomes
//     an 8-block fixup using decide's reassigned-index list (exact).
//   * stau kernel exports -1/stau (mul not div in 4M-elem density passes).
// ---------------------------------------------------------------------------

#define DELTA_F 0.13533528323661270f  // float(exp(-2))
#define MBYTE (1u << 20)

typedef __bf16 bf16;
typedef bf16 bf16x8 __attribute__((ext_vector_type(8)));
typedef bf16 bf16x4 __attribute__((ext_vector_type(4)));
typedef float f32x4 __attribute__((ext_vector_type(4)));

typedef __attribute__((address_space(1))) void as1_void;
typedef __attribute__((address_space(3))) void as3_void;

__device__ __forceinline__ void gload16(const bf16* g, bf16* l) {
  __builtin_amdgcn_global_load_lds((as1_void*)g, (as3_void*)l, 16, 0, 0);
}

// ------------------------------- GEMM --------------------------------------
// C[2048, NB] = A[2048,K] * Bm[NB,K]^T, 128x128 tiles, 8 waves = 2m x 2n x 2k,
// BK=64, XOR-swizzled LDS (swizzle applied on global source addresses since
// global_load_lds cannot scatter). Per-block epilogue mode by column range:
//   n0 < 2048 : GRAM  -> G[row*2048+col]=v, SEN[diag]=v, atomicAdd(sumG)
//   n0 >= 2048: SIG   -> sigmoid(v+bias[col-2048]) -> bf16 Hb or f32 Fo
template <bool SIG_B16>
__global__ __launch_bounds__(512, 4) void gemm_fused(
    const bf16* __restrict__ A, const bf16* __restrict__ Bm,
    float* __restrict__ G, bf16* __restrict__ Hb, float* __restrict__ Fo,
    const float* __restrict__ bias, float* __restrict__ SEN,
    float* __restrict__ sumAll, int K, int sigW) {
  __shared__ __align__(16) char smem[32768];
  const int tid = threadIdx.x;
  const int wave = tid >> 6, lane = tid & 63;
  const int quad = lane >> 4, l16 = lane & 15;
  const int kg = wave & 1, wm = (wave >> 1) & 1, wn = (wave >> 2) & 1;
  const int m0 = blockIdx.y * 128, n0 = blockIdx.x * 128;
  const int waveM = wm * 64, waveN = wn * 64;
  const bool isGram = (n0 < 2048);
  // staging lane roles: 8 rows x 8 slots of 16B per gload16
  const int sr8 = lane >> 3, slot = lane & 7;
  const int gk = (slot ^ sr8) * 8;  // swizzled global k-element offset
  const bf16* aSrc = A + (size_t)(m0 + wave * 16 + sr8) * K + gk;
  const bf16* bSrc = Bm + (size_t)(n0 + wave * 16 + sr8) * K + gk;
  char* const aDst = smem + wave * 2048;
  char* const bDst = smem + 16384 + wave * 2048;
  // fragment read offsets (bytes): row*128 + swizzled 16B slot
  const int swz = ((kg * 4 + quad) ^ (l16 & 7)) * 16;
  const int aOff = (waveM + l16) * 128 + swz;
  const int bOff = 16384 + (waveN + l16) * 128 + swz;

  f32x4 acc[4][4] = {};

  for (int k0 = 0; k0 < K; k0 += 64) {
    gload16(aSrc + k0, (bf16*)aDst);
    gload16(aSrc + 8 * (size_t)K + k0, (bf16*)(aDst + 1024));
    gload16(bSrc + k0, (bf16*)bDst);
    gload16(bSrc + 8 * (size_t)K + k0, (bf16*)(bDst + 1024));
    __syncthreads();
    bf16x8 af[4], bfr[4];
#pragma unroll
    for (int i = 0; i < 4; ++i) af[i] = *(const bf16x8*)(smem + aOff + i * 2048);
#pragma unroll
    for (int j = 0; j < 4; ++j) bfr[j] = *(const bf16x8*)(smem + bOff + j * 2048);
#pragma unroll
    for (int i = 0; i < 4; ++i)
#pragma unroll
      for (int j = 0; j < 4; ++j)
        acc[i][j] = __builtin_amdgcn_mfma_f32_16x16x32_bf16(af[i], bfr[j], acc[i][j], 0, 0, 0);
    __syncthreads();
  }

  // epilogue: merge kg=1 partials into kg=0 via LDS (2 rounds of 2 i's)
  float gsum = 0.f;
  char* const ex = smem + (wn * 2 + wm) * 8192;
#pragma unroll
  for (int round = 0; round < 2; ++round) {
    __syncthreads();
    if (kg == 1) {
#pragma unroll
      for (int ii = 0; ii < 2; ++ii)
#pragma unroll
        for (int j = 0; j < 4; ++j)
          *(f32x4*)(ex + (ii * 4 + j) * 1024 + lane * 16) = acc[round * 2 + ii][j];
    }
    __syncthreads();
    if (kg == 0) {
#pragma unroll
      for (int ii = 0; ii < 2; ++ii) {
        const int i = round * 2 + ii;
#pragma unroll
        for (int j = 0; j < 4; ++j) {
          f32x4 v = acc[i][j] + *(const f32x4*)(ex + (ii * 4 + j) * 1024 + lane * 16);
          const int col = n0 + waveN + j * 16 + l16;
          const float bv = isGram ? 0.f : bias[col - 2048];
#pragma unroll
          for (int r = 0; r < 4; ++r) {
            const int row = m0 + waveM + i * 16 + quad * 4 + r;
            if (isGram) {
              const float val = v[r];
              G[(size_t)row * 2048 + col] = val;
              gsum += val;
              if (row == col) SEN[row] = val;
            } else {
              const float hv = 1.0f / (1.0f + expf(-(v[r] + bv)));
              const int c2 = col - 2048;
              if (SIG_B16) Hb[(size_t)row * 2048 + c2] = (bf16)hv;
              else Fo[(size_t)row * sigW + c2] = hv;
            }
          }
        }
      }
    }
  }
  if (isGram && kg == 0) {
    for (int off = 32; off > 0; off >>= 1) gsum += __shfl_down(gsum, off, 64);
    if (lane == 0) atomicAdd(sumAll, gsum);
  }
}

// --------------------------- small kernels ---------------------------------
__device__ __forceinline__ float block_reduce_sum(float s, float* ws4) {
  for (int off = 32; off > 0; off >>= 1) s += __shfl_down(s, off, 64);
  const int tid = threadIdx.x;
  if ((tid & 63) == 0) ws4[tid >> 6] = s;
  __syncthreads();
  return ws4[0] + ws4[1] + ws4[2] + ws4[3];
}

// one-shot f32->bf16 of x, W0, W1 (segment sizes baked); also zeroes scal
__global__ void f2b_all(const float* __restrict__ x, const float* __restrict__ W0,
                        const float* __restrict__ W1, bf16* __restrict__ xb,
                        bf16* __restrict__ wb0, bf16* __restrict__ wb1,
                        float* __restrict__ scal) {
  const int idx = (blockIdx.x * 256 + threadIdx.x) * 4;
  if (blockIdx.x == 0 && threadIdx.x < 16) scal[threadIdx.x] = 0.f;
  const float* src;
  bf16* dst;
  int off;
  if (idx < 4194304) { src = x; dst = xb; off = idx; }
  else if (idx < 8388608) { src = W0; dst = wb0; off = idx - 4194304; }
  else { src = W1; dst = wb1; off = idx - 8388608; }
  f32x4 v = *(const f32x4*)(src + off);
  bf16x4 o;
  o.x = (bf16)v.x; o.y = (bf16)v.y; o.z = (bf16)v.z; o.w = (bf16)v.w;
  *(bf16x4*)(dst + off) = o;
}

// base[0] = stau = 0.5*(mean(SEN) - sumG/N^2); base[1] = -1/stau
__global__ void stau_kernel(const float* __restrict__ SEN, float* __restrict__ base,
                            int Nsamp) {
  const int tid = threadIdx.x;
  float s = 0.f;
  for (int i = tid; i < Nsamp; i += 256) s += SEN[i];
  __shared__ float ws4[4];
  const float tot = block_reduce_sum(s, ws4);
  if (tid == 0) {
    const float invN = 1.0f / (float)Nsamp;
    const float stau = 0.5f * (tot * invN - base[2] * invN * invN);
    base[0] = stau;
    base[1] = -1.0f / stau;
  }
}

// e[i] = any j<i with dens>=DELTA;  S[i] = sum_j dens(i,j) over ALL j
__global__ void edgesum_kernel(const float* __restrict__ G, const float* __restrict__ SEN,
                               const float* __restrict__ base, int N,
                               int* __restrict__ e, float* __restrict__ S) {
  const int i = blockIdx.x, tid = threadIdx.x;
  const float ninv = base[1];
  const float si = SEN[i];
  const float* gi = G + (size_t)i * N;
  __shared__ int sflag;
  if (tid == 0) sflag = 0;
  __syncthreads();
  float s = 0.f;
  int f = 0;
  for (int j = tid; j < N; j += 256) {
    const float dens = expf((si + SEN[j] - 2.0f * gi[j]) * ninv);
    s += dens;
    if (j < i && dens >= DELTA_F) f = 1;
  }
  if (f) atomicOr(&sflag, 1);
  __shared__ float ws4[4];
  const float tot = block_reduce_sum(s, ws4);
  __syncthreads();
  if (tid == 0) { e[i] = sflag; S[i] = tot; }
}

// Exact sequential resolution of e[i]==1 samples; prefix-sum compaction.
// Exports the reassigned (non-prototype) index list for the lamb fixup.
__global__ void decide_kernel(const int* __restrict__ e, const float* __restrict__ G,
                              const float* __restrict__ SEN, const float* __restrict__ base,
                              int N, int* __restrict__ newflag, int* __restrict__ assigned,
                              int* __restrict__ rcnt, int* __restrict__ rlist) {
  __shared__ int s_flag[2048];
  __shared__ short s_list[2048];
  __shared__ short s_re[2048];
  __shared__ int s_T, s_reN;
  __shared__ int scan[256];
  __shared__ float rbest[256];
  __shared__ int rbj[256];
  const int tid = threadIdx.x;
  const float ninv = base[1];
  const int per = N / 256;
  int cnt = 0;
  for (int k = 0; k < per; ++k) {
    const int i = tid * per + k;
    const int ei = e[i];
    s_flag[i] = (ei == 0);
    if (ei == 0) { newflag[i] = 1; assigned[i] = i; }
    cnt += ei;
  }
  scan[tid] = cnt;
  if (tid == 0) s_reN = 0;
  __syncthreads();
  for (int off = 1; off < 256; off <<= 1) {
    const int v = scan[tid];
    const int add = (tid >= off) ? scan[tid - off] : 0;
    __syncthreads();
    scan[tid] = v + add;
    __syncthreads();
  }
  int pos = scan[tid] - cnt;
  for (int k = 0; k < per; ++k) {
    const int i = tid * per + k;
    if (!s_flag[i]) s_list[pos++] = (short)i;
  }
  if (tid == 255) s_T = scan[255];
  __syncthreads();
  const int T = s_T;
  for (int t = 0; t < T; ++t) {
    const int i = s_list[t];
    const float si = SEN[i];
    const float* gi = G + (size_t)i * N;
    float best = -1.0f;
    int bestj = 0x7fffffff;
    for (int j = tid; j < i; j += 256) {
      if (s_flag[j]) {
        const float dens = expf((si + SEN[j] - 2.0f * gi[j]) * ninv);
        if (dens > best || (dens == best && j < bestj)) { best = dens; bestj = j; }
      }
    }
    rbest[tid] = best; rbj[tid] = bestj;
    __syncthreads();
    if (tid == 0) {
      float b = -1.0f;
      int bj = 0x7fffffff;
      for (int k = 0; k < 256; ++k)
        if (rbest[k] > b || (rbest[k] == b && rbj[k] < bj)) { b = rbest[k]; bj = rbj[k]; }
      if (b < DELTA_F) { s_flag[i] = 1; newflag[i] = 1; assigned[i] = i; }
      else { newflag[i] = 0; assigned[i] = bj; s_re[s_reN++] = (short)i; }
    }
    __syncthreads();
  }
  const int reN = s_reN;
  for (int t = tid; t < reN; t += 256) rlist[t] = s_re[t];
  if (tid == 0) rcnt[0] = reN;
}

// lamb[n] = dens(n, assigned[n]) / (S[n] - sum over reassigned j of dens(n,j))
__global__ void lamb_fix(const float* __restrict__ G, const float* __restrict__ SEN,
                         const float* __restrict__ base, const float* __restrict__ S,
                         const int* __restrict__ assigned, const int* __restrict__ rcnt,
                         const int* __restrict__ rlist, int N, float* __restrict__ lamb) {
  const int n = blockIdx.x * 256 + threadIdx.x;
  const float ninv = base[1];
  const float sn = SEN[n];
  const float* gn = G + (size_t)n * N;
  const int a = assigned[n];
  const float da = expf((sn + SEN[a] - 2.0f * gn[a]) * ninv);
  float denom = S[n];
  const int rc = rcnt[0];
  for (int t = 0; t < rc; ++t) {
    const int j = rlist[t];
    denom -= expf((sn + SEN[j] - 2.0f * gn[j]) * ninv);
  }
  lamb[n] = da / denom;
}

// ------------------------------- driver ------------------------------------
extern "C" void kernel_launch(void* const* d_in, const int* in_sizes, int n_in,
                              void* d_out, int out_size, void* d_ws, size_t ws_size,
                              hipStream_t stream) {
  const float* x = (const float*)d_in[0];
  const float* W0 = (const float*)d_in[1];
  const float* b0 = (const float*)d_in[2];
  const float* W1 = (const float*)d_in[3];
  const float* b1 = (const float*)d_in[4];
  float* out = (float*)d_out;

  const int N = 2048, DIN = 2048, DH = 2048, DOUT = 1024;

  char* w = (char*)d_ws;
  bf16* xb = (bf16*)(w);                  // 8 MB  bf16(x)      [B' rows 0..2047, L0]
  bf16* wb0 = (bf16*)(w + 8 * MBYTE);     // 8 MB  bf16(W0)     [B' rows 2048..4095, L0]
  bf16* hb = (bf16*)(w + 16 * MBYTE);     // 8 MB  bf16(h)      [B'' rows 0..2047, L1]
  bf16* wb1 = (bf16*)(w + 24 * MBYTE);    // 4 MB  bf16(W1)     [B'' rows 2048..3071, L1]
  float* G = (float*)(w + 28 * MBYTE);    // 16 MB Gram
  float* SEN = (float*)(w + 44 * MBYTE);  // 2048 f32 (diag G)
  float* S = SEN + 2048;                  // 2048 f32 (full density row-sums)
  float* scal = S + 2048;                 // [0..3]=L0 {stau,-1/stau,sumG,pad}, [4..7]=L1
  int* e = (int*)(scal + 16);
  int* nf = e + 2048;
  int* as = nf + 2048;
  int* rcnt = as + 2048;
  int* rlist = rcnt + 16;

  float* lamb0 = out + (size_t)N * DOUT;
  float* lamb1 = lamb0 + N;

  f2b_all<<<10240, 256, 0, stream>>>(x, W0, W1, xb, wb0, wb1, scal);

  // ---------------- layer 0: one fused gemm (G | h) ----------------
  gemm_fused<true><<<dim3(32, 16), 512, 0, stream>>>(
      xb, xb, G, hb, nullptr, b0, SEN, scal + 2, DIN, DH);
  stau_kernel<<<1, 256, 0, stream>>>(SEN, scal + 0, N);
  edgesum_kernel<<<N, 256, 0, stream>>>(G, SEN, scal + 0, N, e, S);
  decide_kernel<<<1, 256, 0, stream>>>(e, G, SEN, scal + 0, N, nf, as, rcnt, rlist);
  lamb_fix<<<N / 256, 256, 0, stream>>>(G, SEN, scal + 0, S, as, rcnt, rlist, N, lamb0);

  // ---------------- layer 1: one fused gemm (G | out) ----------------
  gemm_fused<false><<<dim3(24, 16), 512, 0, stream>>>(
      hb, hb, G, nullptr, out, b1, SEN, scal + 6, DH, DOUT);
  stau_kernel<<<1, 256, 0, stream>>>(SEN, scal + 4, N);
  edgesum_kernel<<<N, 256, 0, stream>>>(G, SEN, scal + 4, N, e, S);
  decide_kernel<<<1, 256, 0, stream>>>(e, G, SEN, scal + 4, N, nf, as, rcnt, rlist);
  lamb_fix<<<N / 256, 256, 0, stream>>>(G, SEN, scal + 4, S, as, rcnt, rlist, N, lamb1);
}